// Round 7
// baseline (49.110 us; speedup 1.0000x reference)
//
#include <hip/hip_runtime.h>
#include <hip/hip_bf16.h>
#include <cstdint>

#define NN 2048
#define FF 64
#define BCC 16

typedef float f32x4 __attribute__((ext_vector_type(4)));
typedef __bf16 bf16x8 __attribute__((ext_vector_type(8)));
typedef uint32_t u32x4 __attribute__((ext_vector_type(4)));
typedef uint32_t u32x2 __attribute__((ext_vector_type(2)));

// ---------------- workspace layout (bytes) ----------------
// xP   : bf16 packed [16][jt=64][nb=4][lane=64][e=8] = 4,194,304  (off 0)
//        element (bc,jt,nb,(g,l15),e) = x[bc][n = jt*32+8g+e][f = nb*16+l15]
// U    : f32 [16][2048] = 131,072  (off 4,194,304)   e^{f2}
// V    : f32 [16][2048] = 131,072  (off 4,325,376)   e^{0.1 f2}
// CI   : f32 [16][2048] = 131,072  (off 4,456,448)   e^{-0.9 f1}
// ADJP : u8  [row=2048][g=4][jt=64] = 524,288 (off 4,587,520)
//        byte (row,g,jt) bits t = adj[row][jt*32+8g+t]
// total ~5.1 MB

// fused prep: blocks [0,512): transpose/pack x + per-row dot/exp tables.
//             blocks [512,4608): adj -> ADJP byte table.
__global__ __launch_bounds__(256) void k_prep(const float* __restrict__ x,
        const int* __restrict__ adj,
        const float* __restrict__ a1, const float* __restrict__ a2,
        __hip_bfloat16* __restrict__ xP, float* __restrict__ U,
        float* __restrict__ V, float* __restrict__ CI,
        unsigned char* __restrict__ ADJP) {
    int wid  = threadIdx.x >> 6;
    int lane = threadIdx.x & 63;

    if (blockIdx.x >= 512) {                 // ---- adj packing ----
        int idx = (blockIdx.x - 512) * 4 + wid;   // row*8 + cg
        int row = idx >> 3, cg = idx & 7;
        const int* p = adj + (size_t)row * NN + cg * 256 + lane;
        unsigned long long m0 = __ballot(p[0]   > 0);
        unsigned long long m1 = __ballot(p[64]  > 0);
        unsigned long long m2 = __ballot(p[128] > 0);
        unsigned long long m3 = __ballot(p[192] > 0);
        if (lane < 32) {
            int q = lane >> 3, s = lane & 7;          // chunk c = cg*4+q
            unsigned long long m = (q == 0) ? m0 : (q == 1) ? m1
                                 : (q == 2) ? m2 : m3;
            unsigned char byte = (unsigned char)(m >> (8 * s));
            int jt = (cg * 4 + q) * 2 + (s >> 2);
            int g  = s & 3;
            ADJP[(size_t)row * 256 + g * 64 + jt] = byte;
        }
        return;
    }

    // ---- x pack + tables ----
    __shared__ float tile[64][65];
    __shared__ float red[2][64][4];
    int bc = blockIdx.x >> 5;
    int n0 = (blockIdx.x & 31) * 64;
    int tx = lane;
    int ty = wid;
    const float* xp = x + ((size_t)bc * NN + n0) * FF;
    #pragma unroll
    for (int k = 0; k < 16; k++) {
        int nl = ty * 16 + k;
        tile[nl][tx] = xp[(size_t)nl * FF + tx];
    }
    __syncthreads();
    // packed fragment-order write (coalesced 16B per lane)
    int g = lane >> 4, l15 = lane & 15;
    int jt0 = n0 >> 5;
    #pragma unroll
    for (int jl = 0; jl < 2; jl++) {
        bf16x8 val;
        #pragma unroll
        for (int e = 0; e < 8; e++)
            val[e] = (__bf16)tile[jl * 32 + 8 * g + e][ty * 16 + l15];
        ((bf16x8*)xP)[(((size_t)bc * 64 + jt0 + jl) * 4 + ty) * 64 + lane] = val;
    }
    // dots: thread handles row tx, f-quarter ty
    float d1 = 0.f, d2 = 0.f;
    #pragma unroll
    for (int i = 0; i < 16; i++) {
        int f = ty * 16 + i;
        float xv = tile[tx][f];
        d1 += xv * a1[f];
        d2 += xv * a2[f];
    }
    red[0][tx][ty] = d1;
    red[1][tx][ty] = d2;
    __syncthreads();
    if (ty == 0) {
        float f1 = red[0][tx][0] + red[0][tx][1] + red[0][tx][2] + red[0][tx][3];
        float f2 = red[1][tx][0] + red[1][tx][1] + red[1][tx][2] + red[1][tx][3];
        int idx = bc * NN + n0 + tx;
        U[idx]  = expf(f2);
        V[idx]  = expf(0.1f * f2);
        CI[idx] = expf(-0.9f * f1);
    }
}

// main: block = (bc, 128-row i-block); 4 waves SPLIT I (wave w owns rows
// [i0+32w, i0+32w+32)). All waves sweep jt 0..63 in lockstep over identical
// xP addresses -> L1 serves 3 of 4 waves. Masks bit-packed, u/v in LDS.
// weights w' = adj * max(u_j, Ci*v_j)  (softmax row-scale invariance).
__global__ __launch_bounds__(256, 1) void k_main(
        const __hip_bfloat16* __restrict__ xP, const float* __restrict__ U,
        const float* __restrict__ V, const float* __restrict__ CI,
        const unsigned char* __restrict__ ADJP, float* __restrict__ out) {
    __shared__ float su[2048];
    __shared__ float sv[2048];

    int tid = threadIdx.x;
    int w = tid >> 6, lane = tid & 63;
    int l15 = lane & 15, g = lane >> 4;

    // XCD swizzle: physical%8 selects XCD; put both iblk-halves of 2 bcs there
    int xcd = blockIdx.x & 7, kk = blockIdx.x >> 3;   // kk in 0..31
    int bc   = (xcd << 1) | (kk >> 4);
    int iblk = kk & 15;
    int i0   = iblk * 128;
    int rb   = i0 + w * 32;     // this wave's 32 rows

    // stage u/v into LDS (coalesced)
    const f32x4* Ug = (const f32x4*)(U + bc * NN);
    const f32x4* Vg = (const f32x4*)(V + bc * NN);
    ((f32x4*)su)[tid]       = Ug[tid];
    ((f32x4*)su)[tid + 256] = Ug[tid + 256];
    ((f32x4*)sv)[tid]       = Vg[tid];
    ((f32x4*)sv)[tid + 256] = Vg[tid + 256];
    float Ci0 = CI[bc * NN + rb + l15];
    float Ci1 = CI[bc * NN + rb + 16 + l15];
    __syncthreads();

    f32x4 acc[2][4];
    #pragma unroll
    for (int a = 0; a < 2; a++)
        #pragma unroll
        for (int nb = 0; nb < 4; nb++)
            acc[a][nb] = (f32x4){0.f, 0.f, 0.f, 0.f};
    f32x4 accz0 = (f32x4){0.f, 0.f, 0.f, 0.f};
    f32x4 accz1 = (f32x4){0.f, 0.f, 0.f, 0.f};
    bf16x8 onesf;
    #pragma unroll
    for (int e = 0; e < 8; e++) onesf[e] = (__bf16)1.0f;

    const u32x4* xPbc = (const u32x4*)xP + (size_t)bc * 16384;
    const unsigned char* mr0 = ADJP + (size_t)(rb + l15) * 256 + g * 64;
    const unsigned char* mr1 = mr0 + 16 * 256;

    // named pipeline registers
    u32x4 A_x0, A_x1, A_x2, A_x3, B_x0, B_x1, B_x2, B_x3;
    u32x2 Ma0, Ma1, Mb0, Mb1;      // chunk masks, rows 0/1, double-buffered

#define LOADX(P, JT) do {                                                     \
        const u32x4* xw_ = xPbc + (((size_t)(JT)) << 8) + lane;               \
        P##x0 = xw_[0]; P##x1 = xw_[64]; P##x2 = xw_[128]; P##x3 = xw_[192];  \
    } while (0)

#define LOADMSK(MP, CH) do {                                                  \
        MP##0 = *(const u32x2*)(mr0 + (CH) * 8);                              \
        MP##1 = *(const u32x2*)(mr1 + (CH) * 8);                              \
    } while (0)

#define COMP(P, MP, JT, PP) do {                                              \
        const int jo_ = (JT) * 32 + 8 * g;                                    \
        f32x4 cu0 = *(const f32x4*)&su[jo_];                                  \
        f32x4 cu1 = *(const f32x4*)&su[jo_ + 4];                              \
        f32x4 cv0 = *(const f32x4*)&sv[jo_];                                  \
        f32x4 cv1 = *(const f32x4*)&sv[jo_ + 4];                              \
        uint32_t mb0_ = (MP##0[(PP) >> 2] >> (((PP) & 3) * 8)) & 0xffu;       \
        uint32_t mb1_ = (MP##1[(PP) >> 2] >> (((PP) & 3) * 8)) & 0xffu;       \
        bf16x8 af0_, af1_;                                                    \
        _Pragma("unroll")                                                     \
        for (int t = 0; t < 8; t++) {                                         \
            float uu_ = (t < 4) ? cu0[t] : cu1[t - 4];                        \
            float vv_ = (t < 4) ? cv0[t] : cv1[t - 4];                        \
            uint32_t k0_ = (uint32_t)(((int32_t)(mb0_ << (31 - t))) >> 31);   \
            uint32_t k1_ = (uint32_t)(((int32_t)(mb1_ << (31 - t))) >> 31);   \
            float m0_ = fmaxf(uu_, Ci0 * vv_);                                \
            float m1_ = fmaxf(uu_, Ci1 * vv_);                                \
            af0_[t] = (__bf16)__builtin_bit_cast(float,                       \
                        __builtin_bit_cast(uint32_t, m0_) & k0_);             \
            af1_[t] = (__bf16)__builtin_bit_cast(float,                       \
                        __builtin_bit_cast(uint32_t, m1_) & k1_);             \
        }                                                                     \
        acc[0][0] = __builtin_amdgcn_mfma_f32_16x16x32_bf16(af0_,             \
            __builtin_bit_cast(bf16x8, P##x0), acc[0][0], 0, 0, 0);           \
        acc[0][1] = __builtin_amdgcn_mfma_f32_16x16x32_bf16(af0_,             \
            __builtin_bit_cast(bf16x8, P##x1), acc[0][1], 0, 0, 0);           \
        acc[0][2] = __builtin_amdgcn_mfma_f32_16x16x32_bf16(af0_,             \
            __builtin_bit_cast(bf16x8, P##x2), acc[0][2], 0, 0, 0);           \
        acc[0][3] = __builtin_amdgcn_mfma_f32_16x16x32_bf16(af0_,             \
            __builtin_bit_cast(bf16x8, P##x3), acc[0][3], 0, 0, 0);           \
        accz0     = __builtin_amdgcn_mfma_f32_16x16x32_bf16(af0_,             \
            onesf, accz0, 0, 0, 0);                                           \
        acc[1][0] = __builtin_amdgcn_mfma_f32_16x16x32_bf16(af1_,             \
            __builtin_bit_cast(bf16x8, P##x0), acc[1][0], 0, 0, 0);           \
        acc[1][1] = __builtin_amdgcn_mfma_f32_16x16x32_bf16(af1_,             \
            __builtin_bit_cast(bf16x8, P##x1), acc[1][1], 0, 0, 0);           \
        acc[1][2] = __builtin_amdgcn_mfma_f32_16x16x32_bf16(af1_,             \
            __builtin_bit_cast(bf16x8, P##x2), acc[1][2], 0, 0, 0);           \
        acc[1][3] = __builtin_amdgcn_mfma_f32_16x16x32_bf16(af1_,             \
            __builtin_bit_cast(bf16x8, P##x3), acc[1][3], 0, 0, 0);           \
        accz1     = __builtin_amdgcn_mfma_f32_16x16x32_bf16(af1_,             \
            onesf, accz1, 0, 0, 0);                                           \
    } while (0)

    // chunk = 8 jt (32 KB of xP = L1-sized). Masks prefetched a chunk ahead,
    // xP prefetched one jt ahead. Barrier per chunk bounds wave drift.
#define CHUNK(CH, MP, MN) do {                                                \
        if ((CH) < 7) LOADMSK(MN, (CH) + 1);                                  \
        LOADX(B_, (CH) * 8 + 1); COMP(A_, MP, (CH) * 8 + 0, 0);               \
        LOADX(A_, (CH) * 8 + 2); COMP(B_, MP, (CH) * 8 + 1, 1);               \
        LOADX(B_, (CH) * 8 + 3); COMP(A_, MP, (CH) * 8 + 2, 2);               \
        LOADX(A_, (CH) * 8 + 4); COMP(B_, MP, (CH) * 8 + 3, 3);               \
        LOADX(B_, (CH) * 8 + 5); COMP(A_, MP, (CH) * 8 + 4, 4);               \
        LOADX(A_, (CH) * 8 + 6); COMP(B_, MP, (CH) * 8 + 5, 5);               \
        LOADX(B_, (CH) * 8 + 7); COMP(A_, MP, (CH) * 8 + 6, 6);               \
        if ((CH) < 7) { LOADX(A_, (CH) * 8 + 8); }                            \
        COMP(B_, MP, (CH) * 8 + 7, 7);                                        \
        __syncthreads();                                                      \
    } while (0)

    LOADMSK(Ma, 0);
    LOADX(A_, 0);
    CHUNK(0, Ma, Mb);
    CHUNK(1, Mb, Ma);
    CHUNK(2, Ma, Mb);
    CHUNK(3, Mb, Ma);
    CHUNK(4, Ma, Mb);
    CHUNK(5, Mb, Ma);
    CHUNK(6, Ma, Mb);
    CHUNK(7, Mb, Ma);
#undef LOADX
#undef LOADMSK
#undef COMP
#undef CHUNK

    // epilogue: rows are wave-exclusive; z rows match acc rows -> direct store
    float* outp = out + ((size_t)bc * NN + rb) * FF;
    float zi0[4], zi1[4];
    #pragma unroll
    for (int r = 0; r < 4; r++) {
        zi0[r] = 1.0f / accz0[r];
        zi1[r] = 1.0f / accz1[r];
    }
    #pragma unroll
    for (int nb = 0; nb < 4; nb++)
        #pragma unroll
        for (int r = 0; r < 4; r++) {
            int f = nb * 16 + l15;
            outp[(size_t)(4 * g + r) * FF + f]      = acc[0][nb][r] * zi0[r];
            outp[(size_t)(16 + 4 * g + r) * FF + f] = acc[1][nb][r] * zi1[r];
        }
}

extern "C" void kernel_launch(void* const* d_in, const int* in_sizes, int n_in,
                              void* d_out, int out_size, void* d_ws, size_t ws_size,
                              hipStream_t stream) {
    const float* x  = (const float*)d_in[0];
    const int* adj  = (const int*)d_in[1];
    const float* a1 = (const float*)d_in[2];
    const float* a2 = (const float*)d_in[3];
    float* out = (float*)d_out;

    char* ws = (char*)d_ws;
    __hip_bfloat16* xP = (__hip_bfloat16*)ws;
    float* U  = (float*)(ws + 4194304);
    float* V  = (float*)(ws + 4325376);
    float* CI = (float*)(ws + 4456448);
    unsigned char* ADJP = (unsigned char*)(ws + 4587520);

    k_prep<<<512 + 4096, 256, 0, stream>>>(x, adj, a1, a2, xP, U, V, CI, ADJP);
    k_main<<<256, 256, 0, stream>>>(xP, U, V, CI, ADJP, out);
}

// Round 8
// 26.355 us; speedup vs baseline: 1.8634x; 1.8634x over previous
//
#include <hip/hip_runtime.h>
#include <hip/hip_bf16.h>
#include <cstdint>

#define NN 2048
#define FF 64
#define BCC 16

typedef float f32x4 __attribute__((ext_vector_type(4)));
typedef _Float16 half8 __attribute__((ext_vector_type(8)));
typedef uint32_t u32x4 __attribute__((ext_vector_type(4)));

// ---------------- workspace layout (bytes) ----------------
// xPh  : fp16 packed [16][jt=64][nb=4][lane=64][e=8] = 4,194,304  (off 0)
//        element (bc,jt,nb,(g,l15),e) = x[bc][n = jt*32+8g+e][f = nb*16+l15]
// Uh   : f16 [16][2048] = 65,536  (off 4,194,304)   e^{f2}
// Vh   : f16 [16][2048] = 65,536  (off 4,259,840)   e^{0.1 f2}
// CIh  : f16 [16][2048] = 65,536  (off 4,325,376)   e^{-0.9 f1}
// ADJP : u8  [row=2048][g=4][jt=64] = 524,288 (off 4,390,912)
//        byte (row,g,jt) bits t = adj[row][jt*32+8g+t]
// total ~4.9 MB

// fused prep: blocks [0,512): transpose/pack x + per-row dot/exp tables.
//             blocks [512,4608): adj -> ADJP byte table.
__global__ __launch_bounds__(256) void k_prep(const float* __restrict__ x,
        const int* __restrict__ adj,
        const float* __restrict__ a1, const float* __restrict__ a2,
        _Float16* __restrict__ xP, _Float16* __restrict__ Uh,
        _Float16* __restrict__ Vh, _Float16* __restrict__ CIh,
        unsigned char* __restrict__ ADJP) {
    int wid  = threadIdx.x >> 6;
    int lane = threadIdx.x & 63;

    if (blockIdx.x >= 512) {                 // ---- adj packing ----
        int idx = (blockIdx.x - 512) * 4 + wid;   // row*8 + cg
        int row = idx >> 3, cg = idx & 7;
        const int* p = adj + (size_t)row * NN + cg * 256 + lane;
        unsigned long long m0 = __ballot(p[0]   > 0);
        unsigned long long m1 = __ballot(p[64]  > 0);
        unsigned long long m2 = __ballot(p[128] > 0);
        unsigned long long m3 = __ballot(p[192] > 0);
        if (lane < 32) {
            int q = lane >> 3, s = lane & 7;          // chunk c = cg*4+q
            unsigned long long m = (q == 0) ? m0 : (q == 1) ? m1
                                 : (q == 2) ? m2 : m3;
            unsigned char byte = (unsigned char)(m >> (8 * s));
            int jt = (cg * 4 + q) * 2 + (s >> 2);
            int g  = s & 3;
            ADJP[(size_t)row * 256 + g * 64 + jt] = byte;
        }
        return;
    }

    // ---- x pack + tables ----
    __shared__ float tile[64][65];
    __shared__ float red[2][64][4];
    int bc = blockIdx.x >> 5;
    int n0 = (blockIdx.x & 31) * 64;
    int tx = lane;
    int ty = wid;
    const float* xp = x + ((size_t)bc * NN + n0) * FF;
    #pragma unroll
    for (int k = 0; k < 16; k++) {
        int nl = ty * 16 + k;
        tile[nl][tx] = xp[(size_t)nl * FF + tx];
    }
    __syncthreads();
    // packed fragment-order write (coalesced 16B per lane)
    int g = lane >> 4, l15 = lane & 15;
    int jt0 = n0 >> 5;
    #pragma unroll
    for (int jl = 0; jl < 2; jl++) {
        half8 val;
        #pragma unroll
        for (int e = 0; e < 8; e++)
            val[e] = (_Float16)tile[jl * 32 + 8 * g + e][ty * 16 + l15];
        ((half8*)xP)[(((size_t)bc * 64 + jt0 + jl) * 4 + ty) * 64 + lane] = val;
    }
    // dots: thread handles row tx, f-quarter ty
    float d1 = 0.f, d2 = 0.f;
    #pragma unroll
    for (int i = 0; i < 16; i++) {
        int f = ty * 16 + i;
        float xv = tile[tx][f];
        d1 += xv * a1[f];
        d2 += xv * a2[f];
    }
    red[0][tx][ty] = d1;
    red[1][tx][ty] = d2;
    __syncthreads();
    if (ty == 0) {
        float f1 = red[0][tx][0] + red[0][tx][1] + red[0][tx][2] + red[0][tx][3];
        float f2 = red[1][tx][0] + red[1][tx][1] + red[1][tx][2] + red[1][tx][3];
        int idx = bc * NN + n0 + tx;
        Uh[idx]  = (_Float16)expf(f2);
        Vh[idx]  = (_Float16)expf(0.1f * f2);
        CIh[idx] = (_Float16)expf(-0.9f * f1);
    }
}

// main: block = (bc, 64-row i-block); 4 waves, wave jq owns j-quarter (512 j).
// Each wave: M=64 (4 a-tiles) x F=64 (4 nb), fp16 packed weight math:
//   w' = adj * max(u_j, Ci*v_j)   (softmax row-scale invariance)
// via v_pk_mul_f16 + v_pk_max_f16 + v_and, feeding mfma_f32_16x16x32_f16.
__global__ __launch_bounds__(256) void k_main(
        const _Float16* __restrict__ xP, const _Float16* __restrict__ Uh,
        const _Float16* __restrict__ Vh, const _Float16* __restrict__ CIh,
        const unsigned char* __restrict__ ADJP, float* __restrict__ out) {
    __shared__ _Float16 su[2048];
    __shared__ _Float16 sv[2048];
    __shared__ u32x4 lut[256];
    __shared__ float part[4][16][68];
    __shared__ float zp[4][16];

    int tid = threadIdx.x;
    int jq = tid >> 6, lane = tid & 63;
    int l15 = lane & 15, g = lane >> 4;

    // XCD swizzle: 2 bc per XCD, 32 iblks each
    int xcd = blockIdx.x & 7, kk = blockIdx.x >> 3;   // kk in 0..63
    int bc   = (xcd << 1) | (kk >> 5);
    int iblk = kk & 31;
    int i0   = iblk * 64;

    // stage u/v into LDS (4 KB each; 256 threads x 16 B)
    ((u32x4*)su)[tid] = ((const u32x4*)(Uh + bc * NN))[tid];
    ((u32x4*)sv)[tid] = ((const u32x4*)(Vh + bc * NN))[tid];
    {   // mask LUT: entry b -> 4 u32 AND-masks for fp16 pairs
        uint32_t bb = tid;
        u32x4 lv;
        #pragma unroll
        for (int w = 0; w < 4; w++)
            lv[w] = (((bb >> (2 * w)) & 1u) ? 0xFFFFu : 0u)
                  | (((bb >> (2 * w + 1)) & 1u) ? 0xFFFF0000u : 0u);
        lut[bb] = lv;
    }
    // adjacency bytes for this wave's 16 jt x 4 row-tiles (one-time)
    const unsigned char* ab = ADJP + g * 64 + jq * 16;
    u32x4 adjw0 = *(const u32x4*)(ab + (size_t)(i0 + l15) * 256);
    u32x4 adjw1 = *(const u32x4*)(ab + (size_t)(i0 + 16 + l15) * 256);
    u32x4 adjw2 = *(const u32x4*)(ab + (size_t)(i0 + 32 + l15) * 256);
    u32x4 adjw3 = *(const u32x4*)(ab + (size_t)(i0 + 48 + l15) * 256);
    _Float16 Ci0 = CIh[bc * NN + i0 + l15];
    _Float16 Ci1 = CIh[bc * NN + i0 + 16 + l15];
    _Float16 Ci2 = CIh[bc * NN + i0 + 32 + l15];
    _Float16 Ci3 = CIh[bc * NN + i0 + 48 + l15];
    __syncthreads();

    f32x4 acc[4][4];
    #pragma unroll
    for (int a = 0; a < 4; a++)
        #pragma unroll
        for (int nb = 0; nb < 4; nb++)
            acc[a][nb] = (f32x4){0.f, 0.f, 0.f, 0.f};
    f32x4 accz[4];
    #pragma unroll
    for (int a = 0; a < 4; a++) accz[a] = (f32x4){0.f, 0.f, 0.f, 0.f};
    half8 onesh;
    #pragma unroll
    for (int e = 0; e < 8; e++) onesh[e] = (_Float16)1.0f;

    const u32x4* xPbc = (const u32x4*)xP + (size_t)bc * 16384;

    // named pipeline registers for B fragments
    u32x4 A_x0, A_x1, A_x2, A_x3, B_x0, B_x1, B_x2, B_x3;

#define LOADX(P, J) do {                                                      \
        const u32x4* xw_ = xPbc + (((size_t)(jq * 16 + (J))) << 8) + lane;    \
        P##x0 = xw_[0]; P##x1 = xw_[64]; P##x2 = xw_[128]; P##x3 = xw_[192];  \
    } while (0)

#define GEN(AF, ADJW, CI) do {                                                \
        uint32_t b_ = (ADJW[(J_) >> 2] >> (((J_) & 3) * 8)) & 0xffu;          \
        u32x4 mm_ = lut[b_];                                                  \
        half8 mx_ = __builtin_elementwise_max(uu_, vv_ * (CI));               \
        AF = __builtin_bit_cast(half8, __builtin_bit_cast(u32x4, mx_) & mm_); \
    } while (0)

#define COMP(P, J) do {                                                       \
        const int J_ = (J);                                                   \
        const int jo_ = (jq * 16 + J_) * 32 + 8 * g;                          \
        half8 uu_ = *(const half8*)&su[jo_];                                  \
        half8 vv_ = *(const half8*)&sv[jo_];                                  \
        half8 af0_, af1_, af2_, af3_;                                         \
        GEN(af0_, adjw0, Ci0); GEN(af1_, adjw1, Ci1);                         \
        GEN(af2_, adjw2, Ci2); GEN(af3_, adjw3, Ci3);                         \
        half8 b0_ = __builtin_bit_cast(half8, P##x0);                         \
        half8 b1_ = __builtin_bit_cast(half8, P##x1);                         \
        half8 b2_ = __builtin_bit_cast(half8, P##x2);                         \
        half8 b3_ = __builtin_bit_cast(half8, P##x3);                         \
        acc[0][0] = __builtin_amdgcn_mfma_f32_16x16x32_f16(af0_, b0_, acc[0][0], 0, 0, 0); \
        acc[0][1] = __builtin_amdgcn_mfma_f32_16x16x32_f16(af0_, b1_, acc[0][1], 0, 0, 0); \
        acc[0][2] = __builtin_amdgcn_mfma_f32_16x16x32_f16(af0_, b2_, acc[0][2], 0, 0, 0); \
        acc[0][3] = __builtin_amdgcn_mfma_f32_16x16x32_f16(af0_, b3_, acc[0][3], 0, 0, 0); \
        accz[0]   = __builtin_amdgcn_mfma_f32_16x16x32_f16(af0_, onesh, accz[0], 0, 0, 0); \
        acc[1][0] = __builtin_amdgcn_mfma_f32_16x16x32_f16(af1_, b0_, acc[1][0], 0, 0, 0); \
        acc[1][1] = __builtin_amdgcn_mfma_f32_16x16x32_f16(af1_, b1_, acc[1][1], 0, 0, 0); \
        acc[1][2] = __builtin_amdgcn_mfma_f32_16x16x32_f16(af1_, b2_, acc[1][2], 0, 0, 0); \
        acc[1][3] = __builtin_amdgcn_mfma_f32_16x16x32_f16(af1_, b3_, acc[1][3], 0, 0, 0); \
        accz[1]   = __builtin_amdgcn_mfma_f32_16x16x32_f16(af1_, onesh, accz[1], 0, 0, 0); \
        acc[2][0] = __builtin_amdgcn_mfma_f32_16x16x32_f16(af2_, b0_, acc[2][0], 0, 0, 0); \
        acc[2][1] = __builtin_amdgcn_mfma_f32_16x16x32_f16(af2_, b1_, acc[2][1], 0, 0, 0); \
        acc[2][2] = __builtin_amdgcn_mfma_f32_16x16x32_f16(af2_, b2_, acc[2][2], 0, 0, 0); \
        acc[2][3] = __builtin_amdgcn_mfma_f32_16x16x32_f16(af2_, b3_, acc[2][3], 0, 0, 0); \
        accz[2]   = __builtin_amdgcn_mfma_f32_16x16x32_f16(af2_, onesh, accz[2], 0, 0, 0); \
        acc[3][0] = __builtin_amdgcn_mfma_f32_16x16x32_f16(af3_, b0_, acc[3][0], 0, 0, 0); \
        acc[3][1] = __builtin_amdgcn_mfma_f32_16x16x32_f16(af3_, b1_, acc[3][1], 0, 0, 0); \
        acc[3][2] = __builtin_amdgcn_mfma_f32_16x16x32_f16(af3_, b2_, acc[3][2], 0, 0, 0); \
        acc[3][3] = __builtin_amdgcn_mfma_f32_16x16x32_f16(af3_, b3_, acc[3][3], 0, 0, 0); \
        accz[3]   = __builtin_amdgcn_mfma_f32_16x16x32_f16(af3_, onesh, accz[3], 0, 0, 0); \
    } while (0)

    LOADX(A_, 0);
    LOADX(B_, 1);  COMP(A_, 0);
    LOADX(A_, 2);  COMP(B_, 1);
    LOADX(B_, 3);  COMP(A_, 2);
    LOADX(A_, 4);  COMP(B_, 3);
    LOADX(B_, 5);  COMP(A_, 4);
    LOADX(A_, 6);  COMP(B_, 5);
    LOADX(B_, 7);  COMP(A_, 6);
    LOADX(A_, 8);  COMP(B_, 7);
    LOADX(B_, 9);  COMP(A_, 8);
    LOADX(A_, 10); COMP(B_, 9);
    LOADX(B_, 11); COMP(A_, 10);
    LOADX(A_, 12); COMP(B_, 11);
    LOADX(B_, 13); COMP(A_, 12);
    LOADX(A_, 14); COMP(B_, 13);
    LOADX(B_, 15); COMP(A_, 14);
    COMP(B_, 15);
#undef LOADX
#undef GEN
#undef COMP

    // ---- epilogue: 4 passes (one per a-tile), 18 KB LDS ----
    float* outp = out + ((size_t)bc * NN + i0) * FF;
    #pragma unroll
    for (int a = 0; a < 4; a++) {
        #pragma unroll
        for (int nb = 0; nb < 4; nb++)
            #pragma unroll
            for (int r = 0; r < 4; r++)
                part[jq][4 * g + r][nb * 16 + l15] = acc[a][nb][r];
        if (l15 == 0) {
            #pragma unroll
            for (int r = 0; r < 4; r++)
                zp[jq][4 * g + r] = accz[a][r];
        }
        __syncthreads();
        #pragma unroll
        for (int rr = 0; rr < 4; rr++) {
            int row = jq * 4 + rr;
            float s = part[0][row][lane] + part[1][row][lane]
                    + part[2][row][lane] + part[3][row][lane];
            float z = zp[0][row] + zp[1][row] + zp[2][row] + zp[3][row];
            outp[(size_t)(16 * a + row) * FF + lane] = s / z;
        }
        __syncthreads();
    }
}

extern "C" void kernel_launch(void* const* d_in, const int* in_sizes, int n_in,
                              void* d_out, int out_size, void* d_ws, size_t ws_size,
                              hipStream_t stream) {
    const float* x  = (const float*)d_in[0];
    const int* adj  = (const int*)d_in[1];
    const float* a1 = (const float*)d_in[2];
    const float* a2 = (const float*)d_in[3];
    float* out = (float*)d_out;

    char* ws = (char*)d_ws;
    _Float16* xP  = (_Float16*)ws;
    _Float16* Uh  = (_Float16*)(ws + 4194304);
    _Float16* Vh  = (_Float16*)(ws + 4259840);
    _Float16* CIh = (_Float16*)(ws + 4325376);
    unsigned char* ADJP = (unsigned char*)(ws + 4390912);

    k_prep<<<512 + 4096, 256, 0, stream>>>(x, adj, a1, a2, xP, Uh, Vh, CIh, ADJP);
    k_main<<<512, 256, 0, stream>>>(xP, Uh, Vh, CIh, ADJP, out);
}